// Round 7
// baseline (165.746 us; speedup 1.0000x reference)
//
#include <hip/hip_runtime.h>
#include <hip/hip_bf16.h>

#define S 64
#define HF 128
#define WF 128
#define HW (HF * WF)
#define SSQ (S * S)
#define CCH 256
#define NBOX 128                      // B * N
#define CROPS_ELEMS (134217728)      // NBOX * CCH * S * S
#define CHG 16                        // channels per block (8 float2 groups)
#define NGRP (CCH / CHG)              // 16 channel-group blocks per octant
#define TILE_F2 2000                  // float2 slots per buffer (16 KB); worst octant tile ~43x44 (<1952 incl. pad)

// Barrier that waits ONLY on LDS ops (lgkmcnt); global stores stay in flight.
__device__ __forceinline__ void barrier_lds_only() {
    asm volatile("s_waitcnt lgkmcnt(0)\n\ts_barrier" ::: "memory");
}

// ---------------- Kernel A: per-box theta + M ----------------
__global__ void prep_kernel(const float* __restrict__ obb,
                            float* __restrict__ theta_ws,
                            float* __restrict__ m_out) {
    int i = blockIdx.x * blockDim.x + threadIdx.x;
    if (i >= NBOX) return;
    const float* o = obb + i * 5;
    float cx = o[0], cy = o[1], w = o[2], h = o[3], deg = o[4];
    float cxf = cx * 0.125f;
    float cyf = cy * 0.125f;
    float wf = fmaxf(w, 1.0f) * 1.25f * 0.125f;
    float hf = fmaxf(h, 1.0f) * 1.25f * 0.125f;
    float ang = deg * 0.017453292519943295f;  // deg2rad
    float c_ = cosf(ang);
    float s_ = sinf(ang);
    float sx = wf * (2.0f / (float)WF);
    float sy = hf * (2.0f / (float)HF);
    float tx = cxf * (2.0f / (float)WF) - 1.0f;
    float ty = cyf * (2.0f / (float)HF) - 1.0f;
    float* th = theta_ws + i * 6;
    th[0] = c_ * sx;  th[1] = -s_ * sy; th[2] = tx;
    th[3] = s_ * sx;  th[4] = c_ * sy;  th[5] = ty;

    float A  = c_ * (wf / (float)S);
    float Bv = -s_ * (hf / (float)S);
    float A2 = s_ * (wf / (float)S);
    float B2 = c_ * (hf / (float)S);
    float Cx = cxf - 0.5f * (float)S * (A + Bv);
    float Cy = cyf - 0.5f * (float)S * (A2 + B2);
    float* m = m_out + i * 6;
    m[0] = A;  m[1] = Bv; m[2] = Cx;
    m[3] = A2; m[4] = B2; m[5] = Cy;
}

// Stage one 2-channel tile into an LDS buffer (coalesced row-segment walk).
__device__ __forceinline__ void stage_tile(
        float2* __restrict__ dst, const float* __restrict__ fc,
        int tid, int n, int tw, int twp,
        int qx0, int lidx0, int gidx0, int stepL, int stepG, int rq) {
    int qx_ = qx0, lidx = lidx0, gidx = gidx0;
    for (int q = tid; q < n; q += 256) {
        float2 t;
        t.x = fc[gidx];
        t.y = fc[gidx + HW];
        dst[lidx] = t;
        qx_ += rq; lidx += stepL; gidx += stepG;
        if (qx_ >= tw) { qx_ -= tw; lidx += twp - tw; gidx += WF - tw; }
    }
}

// ---------------- Kernel B: ping-pong float2 LDS tile sampling --------------
// grid: NBOX * 8 octants * NGRP. Block = 256 threads = 16 rows x 16 groups of
// 2 consecutive x (float2 stores). Octant = 32(x) x 16(y) crop pixels.
// 8 phases of 2 channels; stage(next tile) overlaps sample(current tile);
// ONE lgkm-only barrier per phase.
__global__ __launch_bounds__(256, 5) void sample_kernel(
        const float* __restrict__ feat,
        const float* __restrict__ theta,
        float* __restrict__ out) {
    __shared__ float2 tile[2][TILE_F2];

    const int b    = blockIdx.x;
    const int grp  = b & 15;              // % NGRP
    const int oct  = (b >> 4) & 7;
    const int box  = b >> 7;
    const int rx   = oct & 1;             // x half: 0/1
    const int ry   = oct >> 1;            // y quarter: 0..3
    const int tid  = threadIdx.x;

    const float* th = theta + box * 6;
    // feature-pixel affine: ix = ax*fx + bxc*fy + cx_, fx,fy in (-1,1)
    const float ax  = th[0] * 64.0f, bxc = th[1] * 64.0f, cx_ = th[2] * 64.0f + 63.5f;
    const float ay  = th[3] * 64.0f, byc = th[4] * 64.0f, cy_ = th[5] * 64.0f + 63.5f;

    // octant sample-coordinate bbox (+1 for bilinear upper corner)
    const float fcx = (float)((rx << 6) + 32) * 0.015625f - 1.0f;  // region center fx
    const float fcy = (float)((ry << 5) + 16) * 0.015625f - 1.0f;  // region center fy
    const float cxq = ax * fcx + bxc * fcy + cx_;
    const float cyq = ay * fcx + byc * fcy + cy_;
    const float hxq = fabsf(ax) * (31.0f / 64.0f) + fabsf(bxc) * (15.0f / 64.0f);
    const float hyq = fabsf(ay) * (31.0f / 64.0f) + fabsf(byc) * (15.0f / 64.0f);
    const int tx0 = min(max((int)floorf(cxq - hxq), 0), WF - 1);
    const int tx1 = min(max((int)floorf(cxq + hxq) + 1, 0), WF - 1);
    const int ty0 = min(max((int)floorf(cyq - hyq), 0), HF - 1);
    const int ty1 = min(max((int)floorf(cyq + hyq) + 1, 0), HF - 1);
    const int tw  = tx1 - tx0 + 1;
    const int thh = ty1 - ty0 + 1;
    const int twp = tw | 1;               // odd float2-slot row stride
    const int n   = tw * thh;

    // tile-loader walking state (no division inside phases)
    const int qy0_ = tid / tw;
    const int qx0_ = tid - qy0_ * tw;
    const int kq   = 256 / tw;
    const int rq   = 256 - kq * tw;
    const int lidx0 = qy0_ * twp + qx0_;
    const int gidx0 = (ty0 + qy0_) * WF + tx0 + qx0_;
    const int stepL = kq * twp + rq;
    const int stepG = (kq << 7) + rq;

    const float* fmb = feat + (size_t)(box >> 6) * (size_t)(CCH * HW)
                            + (size_t)(grp * CHG) * HW;

    // ---- issue first stage early (hides under per-pixel param math) ----
    stage_tile(&tile[0][0], fmb, tid, n, tw, twp,
               qx0_, lidx0, gidx0, stepL, stepG, rq);

    // this thread's 2 consecutive-x pixels
    const int r     = tid >> 4;           // 0..15 (row in octant)
    const int g     = tid & 15;           // 0..15
    const int y     = (ry << 4) + r;
    const int xbase = (rx << 5) + (g << 1);

    int   pk [2];
    float W00[2], W10[2], W01[2], W11[2];
    {
        float fy = (float)(2 * y + 1) * 0.015625f - 1.0f;
#pragma unroll
        for (int j = 0; j < 2; ++j) {
            int x = xbase + j;
            float fx = (float)(2 * x + 1) * 0.015625f - 1.0f;
            float ix = ax * fx + bxc * fy + cx_;
            float iy = ay * fx + byc * fy + cy_;
            float x0f = floorf(ix), y0f = floorf(iy);
            int x0 = (int)x0f, y0 = (int)y0f;
            float wx1 = ix - x0f, wy1 = iy - y0f;
            float wx0 = 1.0f - wx1, wy0 = 1.0f - wy1;
            bool vx0 = (x0 >= 0) & (x0 < WF);
            bool vx1 = (x0 >= -1) & (x0 < WF - 1);
            bool vy0 = (y0 >= 0) & (y0 < HF);
            bool vy1 = (y0 >= -1) & (y0 < HF - 1);
            W00[j] = (vx0 & vy0) ? wx0 * wy0 : 0.0f;
            W10[j] = (vx1 & vy0) ? wx1 * wy0 : 0.0f;
            W01[j] = (vx0 & vy1) ? wx0 * wy1 : 0.0f;
            W11[j] = (vx1 & vy1) ? wx1 * wy1 : 0.0f;
            int x0c = min(max(x0, 0), WF - 1) - tx0;
            int y0c = min(max(y0, 0), HF - 1) - ty0;
            int x1c = min(max(x0 + 1, 0), WF - 1) - tx0;
            int y1c = min(max(y0 + 1, 0), HF - 1) - ty0;
            int xs = x1c - x0c;           // 0 or 1
            int ys = y1c - y0c;           // 0 or 1
            pk[j] = (y0c * twp + x0c) | (xs << 16) | (ys << 17);
        }
    }

    float* ob = out + (size_t)box * (size_t)(CCH * SSQ)
                    + (size_t)(grp * CHG) * SSQ + y * S + xbase;

#pragma unroll
    for (int cg = 0; cg < CHG / 2; ++cg) {
        // one barrier per phase: ensures (a) current tile's ds_writes done,
        // (b) previous phase's reads of the buffer we are about to overwrite done.
        barrier_lds_only();

        // stage NEXT 2-channel tile into the other buffer (overlaps sampling)
        if (cg < CHG / 2 - 1) {
            stage_tile(&tile[(cg + 1) & 1][0],
                       fmb + (size_t)(2 * (cg + 1)) * HW,
                       tid, n, tw, twp,
                       qx0_, lidx0, gidx0, stepL, stepG, rq);
        }

        // sample CURRENT tile: 2 px x 2 channels
        const float2* src = &tile[cg & 1][0];
        float2 v0, v1;
        float* vp0 = &v0.x;
        float* vp1 = &v1.x;
#pragma unroll
        for (int j = 0; j < 2; ++j) {
            int p   = pk[j];
            int a00 = p & 0xFFFF;
            int xs  = (p >> 16) & 1;
            int a01 = a00 + (((p >> 17) & 1) ? twp : 0);
            float2 c00 = src[a00];
            float2 c10 = src[a00 + xs];
            float2 c01 = src[a01];
            float2 c11 = src[a01 + xs];
            vp0[j] = c00.x * W00[j] + c10.x * W10[j] + c01.x * W01[j] + c11.x * W11[j];
            vp1[j] = c00.y * W00[j] + c10.y * W10[j] + c01.y * W01[j] + c11.y * W11[j];
        }
        float* oc = ob + (size_t)(2 * cg) * SSQ;
        *reinterpret_cast<float2*>(oc)       = v0;
        *reinterpret_cast<float2*>(oc + SSQ) = v1;
    }
}

extern "C" void kernel_launch(void* const* d_in, const int* in_sizes, int n_in,
                              void* d_out, int out_size, void* d_ws, size_t ws_size,
                              hipStream_t stream) {
    const float* feat = (const float*)d_in[0];
    const float* obb  = (const float*)d_in[1];
    float* out = (float*)d_out;
    float* theta_ws = (float*)d_ws;
    float* m_out = out + CROPS_ELEMS;

    prep_kernel<<<1, 128, 0, stream>>>(obb, theta_ws, m_out);
    sample_kernel<<<NBOX * 8 * NGRP, 256, 0, stream>>>(feat, theta_ws, out);
}